// Round 1
// baseline (467.893 us; speedup 1.0000x reference)
//
#include <hip/hip_runtime.h>

// PLIF: v[t] = clamp-reset( v[t-1]*decay + x[t] ), zero-reset at v >= 1.0.
// T=16, spatial = N*C*H*W = 16*64*64*64 = 4194304 elements.
// Pure HBM-bandwidth kernel: 256 MiB in + 256 MiB out. One thread per 4
// consecutive floats (float4), v carried in registers across the T scan.

#define T_STEPS 16
#define V_THRESHOLD 1.0f

__global__ __launch_bounds__(256) void plif_kernel(
    const float4* __restrict__ x,      // [T, SPATIAL/4]
    const float*  __restrict__ decay,  // [1]
    float4*       __restrict__ out,    // [T, SPATIAL/4]
    long long     stride4)             // SPATIAL/4
{
    const long long idx = (long long)blockIdx.x * blockDim.x + threadIdx.x;
    if (idx >= stride4) return;
    const float d = decay[0];

    float4 v = make_float4(0.f, 0.f, 0.f, 0.f);
    long long off = idx;
#pragma unroll
    for (int t = 0; t < T_STEPS; ++t) {
        float4 x4 = x[off];
        v.x = fmaf(v.x, d, x4.x); if (v.x >= V_THRESHOLD) v.x = 0.f;
        v.y = fmaf(v.y, d, x4.y); if (v.y >= V_THRESHOLD) v.y = 0.f;
        v.z = fmaf(v.z, d, x4.z); if (v.z >= V_THRESHOLD) v.z = 0.f;
        v.w = fmaf(v.w, d, x4.w); if (v.w >= V_THRESHOLD) v.w = 0.f;
        out[off] = v;
        off += stride4;
    }
}

extern "C" void kernel_launch(void* const* d_in, const int* in_sizes, int n_in,
                              void* d_out, int out_size, void* d_ws, size_t ws_size,
                              hipStream_t stream) {
    const float* x     = (const float*)d_in[0];   // [T,N,C,H,W] fp32
    const float* decay = (const float*)d_in[1];   // [1] fp32
    float* out         = (float*)d_out;           // [T,N,C,H,W] fp32

    const long long total   = in_sizes[0];        // T * SPATIAL
    const long long spatial = total / T_STEPS;    // 4194304
    const long long stride4 = spatial / 4;        // 1048576 float4/timestep

    const int block = 256;
    const int grid  = (int)((stride4 + block - 1) / block);  // 4096

    plif_kernel<<<grid, block, 0, stream>>>(
        (const float4*)x, decay, (float4*)out, stride4);
}